// Round 2
// baseline (420.503 us; speedup 1.0000x reference)
//
#include <hip/hip_runtime.h>
#include <hip/hip_bf16.h>

// Problem constants
#define BB 32
#define SS 1024
#define TT 64
#define HD 1024   // 2H
#define FF 2048   // 4H
#define MM (BB*SS) // 32768

typedef __attribute__((ext_vector_type(4))) float f32x4;
typedef __attribute__((ext_vector_type(8))) short bf16x8;

__device__ __forceinline__ unsigned short f2bf(float f) {
  __hip_bfloat16 h = __float2bfloat16(f);
  return __builtin_bit_cast(unsigned short, h);
}

__device__ __forceinline__ void gll16(const void* g, void* l) {
  __builtin_amdgcn_global_load_lds(
      (const __attribute__((address_space(1))) void*)g,
      (__attribute__((address_space(3))) void*)l, 16, 0, 0);
}

// ---------------------------------------------------------------- converts
__global__ void cvt_bf16_kernel(const float* __restrict__ x,
                                unsigned short* __restrict__ y, int n4) {
  int stride = gridDim.x * blockDim.x;
  for (int i = blockIdx.x * blockDim.x + threadIdx.x; i < n4; i += stride) {
    float4 v = reinterpret_cast<const float4*>(x)[i];
    ushort4 o;
    o.x = f2bf(v.x); o.y = f2bf(v.y); o.z = f2bf(v.z); o.w = f2bf(v.w);
    reinterpret_cast<ushort4*>(y)[i] = o;
  }
}

// transpose+convert: in fp32 [bz][R][C] -> out bf16 [bz][C][R]
__global__ void tcvt_kernel(const float* __restrict__ in,
                            unsigned short* __restrict__ out, int R, int C) {
  __shared__ float tile[32][33];
  const int bz = blockIdx.z;
  const float* ip = in + (size_t)bz * R * C;
  unsigned short* op = out + (size_t)bz * R * C;
  const int c0 = blockIdx.x * 32, r0 = blockIdx.y * 32;
  const int tx = threadIdx.x, ty = threadIdx.y; // (32, 8)
#pragma unroll
  for (int j = 0; j < 4; ++j)
    tile[ty + j * 8][tx] = ip[(size_t)(r0 + ty + j * 8) * C + c0 + tx];
  __syncthreads();
#pragma unroll
  for (int j = 0; j < 4; ++j)
    op[(size_t)(c0 + ty + j * 8) * R + r0 + tx] = f2bf(tile[tx][ty + j * 8]);
}

// ---------------------------------------------------------------- attention
__global__ __launch_bounds__(256) void attn_kernel(
    const unsigned short* __restrict__ hid_bf,   // [B][S][D]
    const unsigned short* __restrict__ tgt_bf,   // [B][T][D]
    const unsigned short* __restrict__ tgtT_bf,  // [B][D][T]
    unsigned short* __restrict__ ti_bf)          // [B][S][D]
{
  __shared__ unsigned short Qs[64 * 32];
  __shared__ unsigned short Ks[64 * 32];
  __shared__ unsigned short Ps[64 * 72];

  const int tid = threadIdx.x;
  const int w = tid >> 6, l = tid & 63;
  const int lrow = l & 15, lk = l >> 4;
  const int b = blockIdx.y;
  const int sbase = blockIdx.x * 64;

  const size_t hbase = ((size_t)b * SS + sbase) * HD;
  const size_t tbase = (size_t)b * TT * HD;
  const int srow = tid >> 2;
  const int scol = (tid & 3) * 8;

  f32x4 accs[4] = {};
  for (int kt = 0; kt < 32; ++kt) {
    const int kk = kt * 32;
    gll16(hid_bf + hbase + (size_t)srow * HD + kk + scol, Qs + w * 512);
    gll16(tgt_bf + tbase + (size_t)srow * HD + kk + scol, Ks + w * 512);
    __syncthreads();
    bf16x8 a = *reinterpret_cast<const bf16x8*>(&Qs[(w * 16 + lrow) * 32 + lk * 8]);
#pragma unroll
    for (int ct = 0; ct < 4; ++ct) {
      bf16x8 bb = *reinterpret_cast<const bf16x8*>(&Ks[(ct * 16 + lrow) * 32 + lk * 8]);
      accs[ct] = __builtin_amdgcn_mfma_f32_16x16x32_bf16(a, bb, accs[ct], 0, 0, 0);
    }
    __syncthreads();
  }

  float p[4][4];
#pragma unroll
  for (int j = 0; j < 4; ++j) {
    float mx = fmaxf(fmaxf(accs[0][j], accs[1][j]), fmaxf(accs[2][j], accs[3][j]));
#pragma unroll
    for (int d = 1; d < 16; d <<= 1) mx = fmaxf(mx, __shfl_xor(mx, d, 64));
    float sum = 0.f;
#pragma unroll
    for (int ct = 0; ct < 4; ++ct) { p[ct][j] = __expf(accs[ct][j] - mx); sum += p[ct][j]; }
#pragma unroll
    for (int d = 1; d < 16; d <<= 1) sum += __shfl_xor(sum, d, 64);
    float inv = 1.f / sum;
#pragma unroll
    for (int ct = 0; ct < 4; ++ct) p[ct][j] *= inv;
  }
#pragma unroll
  for (int j = 0; j < 4; ++j)
#pragma unroll
    for (int ct = 0; ct < 4; ++ct)
      Ps[(w * 16 + lk * 4 + j) * 72 + ct * 16 + lrow] = f2bf(p[ct][j]);
  __syncthreads();

  const size_t tTbase = (size_t)b * HD * TT;
  for (int chunk = 0; chunk < 16; ++chunk) {
    const int colbase = chunk * 64;
    f32x4 acco[4] = {};
#pragma unroll
    for (int kk2 = 0; kk2 < 2; ++kk2) {
      bf16x8 a = *reinterpret_cast<const bf16x8*>(&Ps[(w * 16 + lrow) * 72 + kk2 * 32 + lk * 8]);
#pragma unroll
      for (int ct = 0; ct < 4; ++ct) {
        const unsigned short* gp =
            tgtT_bf + tTbase + (size_t)(colbase + ct * 16 + lrow) * TT + kk2 * 32 + lk * 8;
        bf16x8 bb = *reinterpret_cast<const bf16x8*>(gp);
        acco[ct] = __builtin_amdgcn_mfma_f32_16x16x32_bf16(a, bb, acco[ct], 0, 0, 0);
      }
    }
#pragma unroll
    for (int ct = 0; ct < 4; ++ct)
#pragma unroll
      for (int j = 0; j < 4; ++j)
        ti_bf[hbase + (size_t)(w * 16 + lk * 4 + j) * HD + colbase + ct * 16 + lrow] =
            f2bf(acco[ct][j]);
  }
}

// ---------------------------------------------------------------- transform GEMM
// 256x256 tile, BK=64, 8 waves (2Mx4N), dbuf LDS (128 KiB), st_16x32 swizzle,
// counted vmcnt(8) across raw barriers, setprio around 2nd MFMA cluster.
// out = tanh([hid|ti] @ W + b) + hid_f32.  M=32768, K=2048, N=1024.

#define WAIT_LGKM0 do { asm volatile("s_waitcnt lgkmcnt(0)" ::: "memory"); \
                        __builtin_amdgcn_sched_barrier(0); } while (0)

__global__ __launch_bounds__(512, 2) void gemm_kernel(
    const unsigned short* __restrict__ hid_bf,  // [M][1024]
    const unsigned short* __restrict__ ti_bf,   // [M][1024]
    const unsigned short* __restrict__ Wt_bf,   // [1024][2048]  (n-major)
    const float* __restrict__ bias,             // [1024]
    const float* __restrict__ hid_f32,          // [M][1024]
    float* __restrict__ out)                    // [M][1024]
{
  __shared__ unsigned short lds[65536];  // 128 KiB: 2 x (A 32KB + B 32KB)

  const int tid = threadIdx.x;
  const int w = tid >> 6, l = tid & 63;
  const int wm = w >> 2, wn = w & 3;
  const int lrow = l & 15, lk = l >> 4;

  // XCD-aware bijective swizzle (nwg = 512, divisible by 8)
  const int orig = blockIdx.y * 4 + blockIdx.x;
  const int lid = (orig & 7) * 64 + (orig >> 3);
  const int nbase = (lid & 3) * 256;
  const int mbase = (lid >> 2) * 256;

  // staging constants: lane -> (row-in-half, pre-swizzled col chunk)
  const int srow = w * 8 + (l >> 3);                              // 0..63 (+64 for round 1)
  const int scc8 = (((l & 7) ^ (((l >> 5) & 1) << 1)) << 3);      // element col offset

#define STAGE_TILE(t, bufb) do {                                              \
    const int k0_ = (t) * 64;                                                 \
    const unsigned short* As_ = (k0_ < 1024) ? (hid_bf + k0_)                 \
                                             : (ti_bf + (k0_ - 1024));        \
    _Pragma("unroll")                                                         \
    for (int h_ = 0; h_ < 2; ++h_) {                                          \
      _Pragma("unroll")                                                       \
      for (int rd_ = 0; rd_ < 2; ++rd_) {                                     \
        const int r_ = srow + rd_ * 64;                                       \
        gll16(As_ + (size_t)(mbase + h_ * 128 + r_) * HD + scc8,              \
              lds + (bufb) + h_ * 8192 + rd_ * 4096 + w * 512);               \
        gll16(Wt_bf + (size_t)(nbase + h_ * 128 + r_) * FF + k0_ + scc8,      \
              lds + (bufb) + 16384 + h_ * 8192 + rd_ * 4096 + w * 512);       \
      }                                                                       \
    }                                                                         \
  } while (0)

  f32x4 acc[8][4] = {};

  // prologue: stage tiles 0,1; wait tile 0 landed (tile 1 in flight)
  STAGE_TILE(0, 0);
  STAGE_TILE(1, 32768);
  asm volatile("s_waitcnt vmcnt(8)" ::: "memory");
  __builtin_amdgcn_sched_barrier(0);
  __builtin_amdgcn_s_barrier();

#define BODY(t, bufb) do {                                                    \
    const unsigned short* Ab_ = lds + (bufb);                                 \
    const unsigned short* Bb_ = lds + (bufb) + 16384;                         \
    bf16x8 a0[8], a1[8], b0[4], b1[4];                                        \
    _Pragma("unroll")                                                         \
    for (int m_ = 0; m_ < 8; ++m_) {                                          \
      const int row_ = wm * 128 + m_ * 16 + lrow;                             \
      int o0_ = row_ * 64 + lk * 8;      o0_ ^= ((o0_ >> 8) & 1) << 4;        \
      int o1_ = row_ * 64 + 32 + lk * 8; o1_ ^= ((o1_ >> 8) & 1) << 4;        \
      a0[m_] = *reinterpret_cast<const bf16x8*>(Ab_ + o0_);                   \
      a1[m_] = *reinterpret_cast<const bf16x8*>(Ab_ + o1_);                   \
    }                                                                         \
    _Pragma("unroll")                                                         \
    for (int n_ = 0; n_ < 4; ++n_) {                                          \
      const int row_ = wn * 64 + n_ * 16 + lrow;                              \
      int o0_ = row_ * 64 + lk * 8;      o0_ ^= ((o0_ >> 8) & 1) << 4;        \
      int o1_ = row_ * 64 + 32 + lk * 8; o1_ ^= ((o1_ >> 8) & 1) << 4;        \
      b0[n_] = *reinterpret_cast<const bf16x8*>(Bb_ + o0_);                   \
      b1[n_] = *reinterpret_cast<const bf16x8*>(Bb_ + o1_);                   \
    }                                                                         \
    _Pragma("unroll")                                                         \
    for (int m_ = 0; m_ < 8; ++m_)                                            \
      _Pragma("unroll")                                                       \
      for (int n_ = 0; n_ < 4; ++n_)                                          \
        acc[m_][n_] = __builtin_amdgcn_mfma_f32_16x16x32_bf16(                \
            a0[m_], b0[n_], acc[m_][n_], 0, 0, 0);                            \
    WAIT_LGKM0;                 /* all reads of this buf retired */           \
    __builtin_amdgcn_s_barrier();                                             \
    if ((t) < 30) { STAGE_TILE((t) + 2, bufb); }                              \
    __builtin_amdgcn_s_setprio(1);                                            \
    _Pragma("unroll")                                                         \
    for (int m_ = 0; m_ < 8; ++m_)                                            \
      _Pragma("unroll")                                                       \
      for (int n_ = 0; n_ < 4; ++n_)                                          \
        acc[m_][n_] = __builtin_amdgcn_mfma_f32_16x16x32_bf16(                \
            a1[m_], b1[n_], acc[m_][n_], 0, 0, 0);                            \
    __builtin_amdgcn_s_setprio(0);                                            \
    if ((t) < 30) { asm volatile("s_waitcnt vmcnt(8)" ::: "memory"); }        \
    else          { asm volatile("s_waitcnt vmcnt(0)" ::: "memory"); }        \
    __builtin_amdgcn_sched_barrier(0);                                        \
    __builtin_amdgcn_s_barrier();                                             \
  } while (0)

  for (int t = 0; t < 32; t += 2) {
    BODY(t, 0);
    BODY(t + 1, 32768);
  }

  // epilogue: tanh + bias + fp32 residual
#pragma unroll
  for (int m = 0; m < 8; ++m) {
    const int row = mbase + wm * 128 + m * 16 + lk * 4;
#pragma unroll
    for (int n = 0; n < 4; ++n) {
      const int col = nbase + wn * 64 + n * 16 + lrow;
      const float bv = bias[col];
#pragma unroll
      for (int j = 0; j < 4; ++j) {
        float x = acc[m][n][j] + bv;
        float xc = fminf(fmaxf(x, -15.f), 15.f);
        float e2 = __expf(2.f * xc);
        float th = (e2 - 1.f) / (e2 + 1.f);
        size_t oi = (size_t)(row + j) * HD + col;
        out[oi] = th + hid_f32[oi];
      }
    }
  }
#undef BODY
#undef STAGE_TILE
}

// ---------------------------------------------------------------- launch
extern "C" void kernel_launch(void* const* d_in, const int* in_sizes, int n_in,
                              void* d_out, int out_size, void* d_ws, size_t ws_size,
                              hipStream_t stream) {
  const float* tgt  = (const float*)d_in[0];  // (B,T,2H)
  const float* hid  = (const float*)d_in[1];  // (B,S,2H)
  const float* W    = (const float*)d_in[2];  // (4H,2H)
  const float* bias = (const float*)d_in[3];  // (2H,)
  float* out = (float*)d_out;

  char* ws = (char*)d_ws;
  unsigned short* hid_bf  = (unsigned short*)(ws);                    //  64 MiB
  unsigned short* ti_bf   = (unsigned short*)(ws + 67108864);         //  64 MiB
  unsigned short* tgt_bf  = (unsigned short*)(ws + 134217728);        //   4 MiB
  unsigned short* tgtT_bf = (unsigned short*)(ws + 138412032);        //   4 MiB
  unsigned short* Wt_bf   = (unsigned short*)(ws + 142606336);        //   4 MiB

  cvt_bf16_kernel<<<2048, 256, 0, stream>>>(hid, hid_bf, (BB * SS * HD) / 4);
  cvt_bf16_kernel<<<512, 256, 0, stream>>>(tgt, tgt_bf, (BB * TT * HD) / 4);
  tcvt_kernel<<<dim3(HD / 32, TT / 32, BB), dim3(32, 8), 0, stream>>>(tgt, tgtT_bf, TT, HD);
  tcvt_kernel<<<dim3(HD / 32, FF / 32, 1), dim3(32, 8), 0, stream>>>(W, Wt_bf, FF, HD);
  attn_kernel<<<dim3(SS / 64, BB), 256, 0, stream>>>(hid_bf, tgt_bf, tgtT_bf, ti_bf);
  gemm_kernel<<<dim3(HD / 128 / 2, MM / 256), 512, 0, stream>>>(hid_bf, ti_bf, Wt_bf, bias, hid, out);
}

// Round 3
// 258.048 us; speedup vs baseline: 1.6296x; 1.6296x over previous
//
#include <hip/hip_runtime.h>
#include <hip/hip_bf16.h>

// Problem constants
#define BB 32
#define SS 1024
#define TT 64
#define HD 1024   // 2H
#define FF 2048   // 4H
#define MM (BB*SS) // 32768

typedef __attribute__((ext_vector_type(4))) float f32x4;
typedef __attribute__((ext_vector_type(8))) short bf16x8;

__device__ __forceinline__ unsigned short f2bf(float f) {
  __hip_bfloat16 h = __float2bfloat16(f);
  return __builtin_bit_cast(unsigned short, h);
}

__device__ __forceinline__ void gll16(const void* g, void* l) {
  __builtin_amdgcn_global_load_lds(
      (const __attribute__((address_space(1))) void*)g,
      (__attribute__((address_space(3))) void*)l, 16, 0, 0);
}

// ---------------------------------------------------------------- converts
__global__ void cvt_bf16_kernel(const float* __restrict__ x,
                                unsigned short* __restrict__ y, int n4) {
  int stride = gridDim.x * blockDim.x;
  for (int i = blockIdx.x * blockDim.x + threadIdx.x; i < n4; i += stride) {
    float4 v = reinterpret_cast<const float4*>(x)[i];
    ushort4 o;
    o.x = f2bf(v.x); o.y = f2bf(v.y); o.z = f2bf(v.z); o.w = f2bf(v.w);
    reinterpret_cast<ushort4*>(y)[i] = o;
  }
}

// transpose+convert: in fp32 [bz][R][C] -> out bf16 [bz][C][R]
__global__ void tcvt_kernel(const float* __restrict__ in,
                            unsigned short* __restrict__ out, int R, int C) {
  __shared__ float tile[32][33];
  const int bz = blockIdx.z;
  const float* ip = in + (size_t)bz * R * C;
  unsigned short* op = out + (size_t)bz * R * C;
  const int c0 = blockIdx.x * 32, r0 = blockIdx.y * 32;
  const int tx = threadIdx.x, ty = threadIdx.y; // (32, 8)
#pragma unroll
  for (int j = 0; j < 4; ++j)
    tile[ty + j * 8][tx] = ip[(size_t)(r0 + ty + j * 8) * C + c0 + tx];
  __syncthreads();
#pragma unroll
  for (int j = 0; j < 4; ++j)
    op[(size_t)(c0 + ty + j * 8) * R + r0 + tx] = f2bf(tile[tx][ty + j * 8]);
}

// ---------------------------------------------------------------- attention
__global__ __launch_bounds__(256) void attn_kernel(
    const unsigned short* __restrict__ hid_bf,   // [B][S][D]
    const unsigned short* __restrict__ tgt_bf,   // [B][T][D]
    const unsigned short* __restrict__ tgtT_bf,  // [B][D][T]
    unsigned short* __restrict__ ti_bf)          // [B][S][D]
{
  __shared__ unsigned short Qs[64 * 32];
  __shared__ unsigned short Ks[64 * 32];
  __shared__ unsigned short Ps[64 * 72];

  const int tid = threadIdx.x;
  const int w = tid >> 6, l = tid & 63;
  const int lrow = l & 15, lk = l >> 4;
  const int b = blockIdx.y;
  const int sbase = blockIdx.x * 64;

  const size_t hbase = ((size_t)b * SS + sbase) * HD;
  const size_t tbase = (size_t)b * TT * HD;
  const int srow = tid >> 2;
  const int scol = (tid & 3) * 8;

  f32x4 accs[4] = {};
  for (int kt = 0; kt < 32; ++kt) {
    const int kk = kt * 32;
    gll16(hid_bf + hbase + (size_t)srow * HD + kk + scol, Qs + w * 512);
    gll16(tgt_bf + tbase + (size_t)srow * HD + kk + scol, Ks + w * 512);
    __syncthreads();
    bf16x8 a = *reinterpret_cast<const bf16x8*>(&Qs[(w * 16 + lrow) * 32 + lk * 8]);
#pragma unroll
    for (int ct = 0; ct < 4; ++ct) {
      bf16x8 bb = *reinterpret_cast<const bf16x8*>(&Ks[(ct * 16 + lrow) * 32 + lk * 8]);
      accs[ct] = __builtin_amdgcn_mfma_f32_16x16x32_bf16(a, bb, accs[ct], 0, 0, 0);
    }
    __syncthreads();
  }

  float p[4][4];
#pragma unroll
  for (int j = 0; j < 4; ++j) {
    float mx = fmaxf(fmaxf(accs[0][j], accs[1][j]), fmaxf(accs[2][j], accs[3][j]));
#pragma unroll
    for (int d = 1; d < 16; d <<= 1) mx = fmaxf(mx, __shfl_xor(mx, d, 64));
    float sum = 0.f;
#pragma unroll
    for (int ct = 0; ct < 4; ++ct) { p[ct][j] = __expf(accs[ct][j] - mx); sum += p[ct][j]; }
#pragma unroll
    for (int d = 1; d < 16; d <<= 1) sum += __shfl_xor(sum, d, 64);
    float inv = 1.f / sum;
#pragma unroll
    for (int ct = 0; ct < 4; ++ct) p[ct][j] *= inv;
  }
#pragma unroll
  for (int j = 0; j < 4; ++j)
#pragma unroll
    for (int ct = 0; ct < 4; ++ct)
      Ps[(w * 16 + lk * 4 + j) * 72 + ct * 16 + lrow] = f2bf(p[ct][j]);
  __syncthreads();

  const size_t tTbase = (size_t)b * HD * TT;
  for (int chunk = 0; chunk < 16; ++chunk) {
    const int colbase = chunk * 64;
    f32x4 acco[4] = {};
#pragma unroll
    for (int kk2 = 0; kk2 < 2; ++kk2) {
      bf16x8 a = *reinterpret_cast<const bf16x8*>(&Ps[(w * 16 + lrow) * 72 + kk2 * 32 + lk * 8]);
#pragma unroll
      for (int ct = 0; ct < 4; ++ct) {
        const unsigned short* gp =
            tgtT_bf + tTbase + (size_t)(colbase + ct * 16 + lrow) * TT + kk2 * 32 + lk * 8;
        bf16x8 bb = *reinterpret_cast<const bf16x8*>(gp);
        acco[ct] = __builtin_amdgcn_mfma_f32_16x16x32_bf16(a, bb, acco[ct], 0, 0, 0);
      }
    }
#pragma unroll
    for (int ct = 0; ct < 4; ++ct)
#pragma unroll
      for (int j = 0; j < 4; ++j)
        ti_bf[hbase + (size_t)(w * 16 + lk * 4 + j) * HD + colbase + ct * 16 + lrow] =
            f2bf(acco[ct][j]);
  }
}

// ---------------------------------------------------------------- transform GEMM
// m201-style 256x256 / BK=64 / 8 waves (2Mx4N) / 8-phase per 2 K-tiles.
// LDS 128KB: 2 bufs x { A: 2x16KB halves, B: 2x16KB halves }, 3-bit XOR swizzle.
// Per phase: ds_read quadrant frags || stage one 16KB half (2 gll16) ->
// barrier -> lgkm(0) -> setprio(1) -> 16 MFMA -> setprio(0) -> barrier.
// vmcnt(4) once per K-tile (phase 4/8). Stage schedule: tile tt stages
// A0,A1(tt+1)->other buf (P0,P1); B0,B1(tt+2)->own buf (P2,P3).

__global__ __launch_bounds__(512) void gemm_kernel(
    const unsigned short* __restrict__ hid_bf,  // [M][1024]
    const unsigned short* __restrict__ ti_bf,   // [M][1024]
    const unsigned short* __restrict__ Wt_bf,   // [1024][2048]  (n-major)
    const float* __restrict__ bias,             // [1024]
    const float* __restrict__ hid_f32,          // [M][1024]
    float* __restrict__ out)                    // [M][1024]
{
  __shared__ unsigned short lds[65536];  // 128 KiB

  const int tid = threadIdx.x;
  const int w = tid >> 6, l = tid & 63;
  const int wm = w >> 2, wn = w & 3;       // 2 x 4 wave grid
  const int lrow = l & 15, lk = l >> 4;

  // XCD-aware bijective swizzle (nwg = 512, divisible by 8)
  const int orig = blockIdx.y * 4 + blockIdx.x;
  const int lid = (orig & 7) * 64 + (orig >> 3);
  const int nbase = (lid & 3) * 256;
  const int mbase = (lid >> 2) * 256;

  // staging lane geometry: row-in-half = rd*64 + srow8; col chunk pre-swizzled
  const int srow8 = w * 8 + (l >> 3);           // 0..63
  const int scol = ((l & 7) ^ (l >> 3)) << 3;   // element col offset (swizzled)

  // ds_read swizzled chunk offsets (elements): chunk (kh*4+lk) ^ (row&7)
  const int ck0 = ((lk)     ^ (lrow & 7)) << 3;
  const int ck1 = ((4 + lk) ^ (lrow & 7)) << 3;

#define STAGE_A(s, bsel, h) do {                                               \
    const int k0_ = (s) * 64;                                                  \
    const unsigned short* p_ = (k0_ < 1024) ? (hid_bf + k0_)                   \
                                            : (ti_bf + (k0_ - 1024));          \
    _Pragma("unroll")                                                          \
    for (int rd_ = 0; rd_ < 2; ++rd_)                                          \
      gll16(p_ + (size_t)(mbase + (h) * 128 + rd_ * 64 + srow8) * HD + scol,   \
            lds + (bsel) * 32768 + (h) * 8192 + rd_ * 4096 + w * 512);         \
  } while (0)

#define STAGE_B(s, bsel, h) do {                                               \
    const int k0_ = (s) * 64;                                                  \
    _Pragma("unroll")                                                          \
    for (int rd_ = 0; rd_ < 2; ++rd_)                                          \
      gll16(Wt_bf + (size_t)(nbase + (h) * 128 + rd_ * 64 + srow8) * FF        \
                  + k0_ + scol,                                                \
            lds + (bsel) * 32768 + 16384 + (h) * 8192 + rd_ * 4096 + w * 512); \
  } while (0)

#define PH_MID do {                                                            \
    __builtin_amdgcn_s_barrier();                                              \
    asm volatile("s_waitcnt lgkmcnt(0)" ::: "memory");                         \
    __builtin_amdgcn_sched_barrier(0);                                         \
    __builtin_amdgcn_s_setprio(1);                                             \
  } while (0)

#define PH_END do {                                                            \
    __builtin_amdgcn_s_setprio(0);                                             \
    __builtin_amdgcn_s_barrier();                                              \
  } while (0)

  f32x4 acc[8][4] = {};
  bf16x8 aR[4][2], bR[4][2];

  // prologue: A0,A1,B0,B1(tile0); B0,B1(tile1). vmcnt(4) -> tile0 landed.
  STAGE_A(0, 0, 0); STAGE_A(0, 0, 1);
  STAGE_B(0, 0, 0); STAGE_B(0, 0, 1);
  STAGE_B(1, 1, 0); STAGE_B(1, 1, 1);
  asm volatile("s_waitcnt vmcnt(4)" ::: "memory");
  __builtin_amdgcn_sched_barrier(0);
  __builtin_amdgcn_s_barrier();

#define TILE(tt, c) do {                                                       \
    const int sa_ = ((tt) + 1 > 31) ? 31 : (tt) + 1;                           \
    const int sb_ = ((tt) + 2 > 31) ? 31 : (tt) + 2;                           \
    const int abase_ = (c) * 32768 + wm * 8192 + lrow * 64;                    \
    const int bbase_ = (c) * 32768 + 16384 + (wn >> 1) * 8192                  \
                       + ((wn & 1) * 64 + lrow) * 64;                          \
    /* ---- P0: a[0..3], b[0..1]; stage A0(tt+1); MFMA m0-3 x n0-1 ---- */     \
    _Pragma("unroll")                                                          \
    for (int m_ = 0; m_ < 4; ++m_) {                                           \
      aR[m_][0] = *(const bf16x8*)(lds + abase_ + m_ * 1024 + ck0);            \
      aR[m_][1] = *(const bf16x8*)(lds + abase_ + m_ * 1024 + ck1);            \
    }                                                                          \
    _Pragma("unroll")                                                          \
    for (int n_ = 0; n_ < 2; ++n_) {                                           \
      bR[n_][0] = *(const bf16x8*)(lds + bbase_ + n_ * 1024 + ck0);            \
      bR[n_][1] = *(const bf16x8*)(lds + bbase_ + n_ * 1024 + ck1);            \
    }                                                                          \
    STAGE_A(sa_, 1 - (c), 0);                                                  \
    PH_MID;                                                                    \
    _Pragma("unroll")                                                          \
    for (int m_ = 0; m_ < 4; ++m_)                                             \
      _Pragma("unroll")                                                        \
      for (int n_ = 0; n_ < 2; ++n_) {                                         \
        acc[m_][n_] = __builtin_amdgcn_mfma_f32_16x16x32_bf16(                 \
            aR[m_][0], bR[n_][0], acc[m_][n_], 0, 0, 0);                       \
        acc[m_][n_] = __builtin_amdgcn_mfma_f32_16x16x32_bf16(                 \
            aR[m_][1], bR[n_][1], acc[m_][n_], 0, 0, 0);                       \
      }                                                                        \
    PH_END;                                                                    \
    /* ---- P1: b[2..3]; stage A1(tt+1); MFMA m0-3 x n2-3 ---- */              \
    _Pragma("unroll")                                                          \
    for (int n_ = 2; n_ < 4; ++n_) {                                           \
      bR[n_][0] = *(const bf16x8*)(lds + bbase_ + n_ * 1024 + ck0);            \
      bR[n_][1] = *(const bf16x8*)(lds + bbase_ + n_ * 1024 + ck1);            \
    }                                                                          \
    STAGE_A(sa_, 1 - (c), 1);                                                  \
    PH_MID;                                                                    \
    _Pragma("unroll")                                                          \
    for (int m_ = 0; m_ < 4; ++m_)                                             \
      _Pragma("unroll")                                                        \
      for (int n_ = 2; n_ < 4; ++n_) {                                         \
        acc[m_][n_] = __builtin_amdgcn_mfma_f32_16x16x32_bf16(                 \
            aR[m_][0], bR[n_][0], acc[m_][n_], 0, 0, 0);                       \
        acc[m_][n_] = __builtin_amdgcn_mfma_f32_16x16x32_bf16(                 \
            aR[m_][1], bR[n_][1], acc[m_][n_], 0, 0, 0);                       \
      }                                                                        \
    PH_END;                                                                    \
    /* ---- P2: a[4..7] (reuse regs); stage B0(tt+2); MFMA m4-7 x n0-1 ---- */ \
    _Pragma("unroll")                                                          \
    for (int m_ = 0; m_ < 4; ++m_) {                                           \
      aR[m_][0] = *(const bf16x8*)(lds + abase_ + (m_ + 4) * 1024 + ck0);      \
      aR[m_][1] = *(const bf16x8*)(lds + abase_ + (m_ + 4) * 1024 + ck1);      \
    }                                                                          \
    STAGE_B(sb_, (c), 0);                                                      \
    PH_MID;                                                                    \
    _Pragma("unroll")                                                          \
    for (int m_ = 0; m_ < 4; ++m_)                                             \
      _Pragma("unroll")                                                        \
      for (int n_ = 0; n_ < 2; ++n_) {                                         \
        acc[m_ + 4][n_] = __builtin_amdgcn_mfma_f32_16x16x32_bf16(             \
            aR[m_][0], bR[n_][0], acc[m_ + 4][n_], 0, 0, 0);                   \
        acc[m_ + 4][n_] = __builtin_amdgcn_mfma_f32_16x16x32_bf16(             \
            aR[m_][1], bR[n_][1], acc[m_ + 4][n_], 0, 0, 0);                   \
      }                                                                        \
    PH_END;                                                                    \
    /* ---- P3: no reads; stage B1(tt+2); MFMA m4-7 x n2-3; vmcnt(4) ---- */   \
    STAGE_B(sb_, (c), 1);                                                      \
    PH_MID;                                                                    \
    _Pragma("unroll")                                                          \
    for (int m_ = 0; m_ < 4; ++m_)                                             \
      _Pragma("unroll")                                                        \
      for (int n_ = 2; n_ < 4; ++n_) {                                         \
        acc[m_ + 4][n_] = __builtin_amdgcn_mfma_f32_16x16x32_bf16(             \
            aR[m_][0], bR[n_][0], acc[m_ + 4][n_], 0, 0, 0);                   \
        acc[m_ + 4][n_] = __builtin_amdgcn_mfma_f32_16x16x32_bf16(             \
            aR[m_][1], bR[n_][1], acc[m_ + 4][n_], 0, 0, 0);                   \
      }                                                                        \
    __builtin_amdgcn_s_setprio(0);                                             \
    asm volatile("s_waitcnt vmcnt(4)" ::: "memory");                           \
    __builtin_amdgcn_sched_barrier(0);                                         \
    __builtin_amdgcn_s_barrier();                                              \
  } while (0)

  for (int tt = 0; tt < 32; tt += 2) {
    TILE(tt, 0);
    TILE(tt + 1, 1);
  }
#undef TILE
#undef PH_MID
#undef PH_END
#undef STAGE_A
#undef STAGE_B

  // epilogue: tanh + bias + fp32 residual
#pragma unroll
  for (int m = 0; m < 8; ++m) {
    const int row = mbase + wm * 128 + m * 16 + lk * 4;
#pragma unroll
    for (int n = 0; n < 4; ++n) {
      const int col = nbase + wn * 64 + n * 16 + lrow;
      const float bv = bias[col];
#pragma unroll
      for (int j = 0; j < 4; ++j) {
        float x = acc[m][n][j] + bv;
        float xc = fminf(fmaxf(x, -15.f), 15.f);
        float e2 = __expf(2.f * xc);
        float th = (e2 - 1.f) / (e2 + 1.f);
        size_t oi = (size_t)(row + j) * HD + col;
        out[oi] = th + hid_f32[oi];
      }
    }
  }
}

// ---------------------------------------------------------------- launch
extern "C" void kernel_launch(void* const* d_in, const int* in_sizes, int n_in,
                              void* d_out, int out_size, void* d_ws, size_t ws_size,
                              hipStream_t stream) {
  const float* tgt  = (const float*)d_in[0];  // (B,T,2H)
  const float* hid  = (const float*)d_in[1];  // (B,S,2H)
  const float* W    = (const float*)d_in[2];  // (4H,2H)
  const float* bias = (const float*)d_in[3];  // (2H,)
  float* out = (float*)d_out;

  char* ws = (char*)d_ws;
  unsigned short* hid_bf  = (unsigned short*)(ws);                    //  64 MiB
  unsigned short* ti_bf   = (unsigned short*)(ws + 67108864);         //  64 MiB
  unsigned short* tgt_bf  = (unsigned short*)(ws + 134217728);        //   4 MiB
  unsigned short* tgtT_bf = (unsigned short*)(ws + 138412032);        //   4 MiB
  unsigned short* Wt_bf   = (unsigned short*)(ws + 142606336);        //   4 MiB

  cvt_bf16_kernel<<<2048, 256, 0, stream>>>(hid, hid_bf, (BB * SS * HD) / 4);
  cvt_bf16_kernel<<<512, 256, 0, stream>>>(tgt, tgt_bf, (BB * TT * HD) / 4);
  tcvt_kernel<<<dim3(HD / 32, TT / 32, BB), dim3(32, 8), 0, stream>>>(tgt, tgtT_bf, TT, HD);
  tcvt_kernel<<<dim3(HD / 32, FF / 32, 1), dim3(32, 8), 0, stream>>>(W, Wt_bf, FF, HD);
  attn_kernel<<<dim3(SS / 64, BB), 256, 0, stream>>>(hid_bf, tgt_bf, tgtT_bf, ti_bf);
  gemm_kernel<<<dim3(HD / 128 / 2, MM / 256), 512, 0, stream>>>(hid_bf, ti_bf, Wt_bf, bias, hid, out);
}

// Round 4
// 245.004 us; speedup vs baseline: 1.7163x; 1.0532x over previous
//
#include <hip/hip_runtime.h>
#include <hip/hip_bf16.h>

// Problem constants
#define BB 32
#define SS 1024
#define TT 64
#define HD 1024   // 2H
#define FF 2048   // 4H
#define MM (BB*SS) // 32768

typedef __attribute__((ext_vector_type(4))) float f32x4;
typedef __attribute__((ext_vector_type(8))) short bf16x8;

__device__ __forceinline__ unsigned short f2bf(float f) {
  __hip_bfloat16 h = __float2bfloat16(f);
  return __builtin_bit_cast(unsigned short, h);
}

__device__ __forceinline__ void gll16(const void* g, void* l) {
  __builtin_amdgcn_global_load_lds(
      (const __attribute__((address_space(1))) void*)g,
      (__attribute__((address_space(3))) void*)l, 16, 0, 0);
}

// ---------------------------------------------------------------- converts
__global__ void cvt_bf16_kernel(const float* __restrict__ x,
                                unsigned short* __restrict__ y, int n4) {
  int stride = gridDim.x * blockDim.x;
  for (int i = blockIdx.x * blockDim.x + threadIdx.x; i < n4; i += stride) {
    float4 v = reinterpret_cast<const float4*>(x)[i];
    ushort4 o;
    o.x = f2bf(v.x); o.y = f2bf(v.y); o.z = f2bf(v.z); o.w = f2bf(v.w);
    reinterpret_cast<ushort4*>(y)[i] = o;
  }
}

// transpose+convert: in fp32 [bz][R][C] -> out bf16 [bz][C][R]
__global__ void tcvt_kernel(const float* __restrict__ in,
                            unsigned short* __restrict__ out, int R, int C) {
  __shared__ float tile[32][33];
  const int bz = blockIdx.z;
  const float* ip = in + (size_t)bz * R * C;
  unsigned short* op = out + (size_t)bz * R * C;
  const int c0 = blockIdx.x * 32, r0 = blockIdx.y * 32;
  const int tx = threadIdx.x, ty = threadIdx.y; // (32, 8)
#pragma unroll
  for (int j = 0; j < 4; ++j)
    tile[ty + j * 8][tx] = ip[(size_t)(r0 + ty + j * 8) * C + c0 + tx];
  __syncthreads();
#pragma unroll
  for (int j = 0; j < 4; ++j)
    op[(size_t)(c0 + ty + j * 8) * R + r0 + tx] = f2bf(tile[tx][ty + j * 8]);
}

// ---------------------------------------------------------------- attention
__global__ __launch_bounds__(256) void attn_kernel(
    const unsigned short* __restrict__ hid_bf,   // [B][S][D]
    const unsigned short* __restrict__ tgt_bf,   // [B][T][D]
    const unsigned short* __restrict__ tgtT_bf,  // [B][D][T]
    unsigned short* __restrict__ ti_bf)          // [B][S][D]
{
  __shared__ unsigned short Qs[64 * 32];
  __shared__ unsigned short Ks[64 * 32];
  __shared__ unsigned short Ps[64 * 72];

  const int tid = threadIdx.x;
  const int w = tid >> 6, l = tid & 63;
  const int lrow = l & 15, lk = l >> 4;
  const int b = blockIdx.y;
  const int sbase = blockIdx.x * 64;

  const size_t hbase = ((size_t)b * SS + sbase) * HD;
  const size_t tbase = (size_t)b * TT * HD;
  const int srow = tid >> 2;
  const int scol = (tid & 3) * 8;

  f32x4 accs[4] = {};
  for (int kt = 0; kt < 32; ++kt) {
    const int kk = kt * 32;
    gll16(hid_bf + hbase + (size_t)srow * HD + kk + scol, Qs + w * 512);
    gll16(tgt_bf + tbase + (size_t)srow * HD + kk + scol, Ks + w * 512);
    __syncthreads();
    bf16x8 a = *reinterpret_cast<const bf16x8*>(&Qs[(w * 16 + lrow) * 32 + lk * 8]);
#pragma unroll
    for (int ct = 0; ct < 4; ++ct) {
      bf16x8 bb = *reinterpret_cast<const bf16x8*>(&Ks[(ct * 16 + lrow) * 32 + lk * 8]);
      accs[ct] = __builtin_amdgcn_mfma_f32_16x16x32_bf16(a, bb, accs[ct], 0, 0, 0);
    }
    __syncthreads();
  }

  float p[4][4];
#pragma unroll
  for (int j = 0; j < 4; ++j) {
    float mx = fmaxf(fmaxf(accs[0][j], accs[1][j]), fmaxf(accs[2][j], accs[3][j]));
#pragma unroll
    for (int d = 1; d < 16; d <<= 1) mx = fmaxf(mx, __shfl_xor(mx, d, 64));
    float sum = 0.f;
#pragma unroll
    for (int ct = 0; ct < 4; ++ct) { p[ct][j] = __expf(accs[ct][j] - mx); sum += p[ct][j]; }
#pragma unroll
    for (int d = 1; d < 16; d <<= 1) sum += __shfl_xor(sum, d, 64);
    float inv = 1.f / sum;
#pragma unroll
    for (int ct = 0; ct < 4; ++ct) p[ct][j] *= inv;
  }
#pragma unroll
  for (int j = 0; j < 4; ++j)
#pragma unroll
    for (int ct = 0; ct < 4; ++ct)
      Ps[(w * 16 + lk * 4 + j) * 72 + ct * 16 + lrow] = f2bf(p[ct][j]);
  __syncthreads();

  const size_t tTbase = (size_t)b * HD * TT;
  for (int chunk = 0; chunk < 16; ++chunk) {
    const int colbase = chunk * 64;
    f32x4 acco[4] = {};
#pragma unroll
    for (int kk2 = 0; kk2 < 2; ++kk2) {
      bf16x8 a = *reinterpret_cast<const bf16x8*>(&Ps[(w * 16 + lrow) * 72 + kk2 * 32 + lk * 8]);
#pragma unroll
      for (int ct = 0; ct < 4; ++ct) {
        const unsigned short* gp =
            tgtT_bf + tTbase + (size_t)(colbase + ct * 16 + lrow) * TT + kk2 * 32 + lk * 8;
        bf16x8 bb = *reinterpret_cast<const bf16x8*>(gp);
        acco[ct] = __builtin_amdgcn_mfma_f32_16x16x32_bf16(a, bb, acco[ct], 0, 0, 0);
      }
    }
#pragma unroll
    for (int ct = 0; ct < 4; ++ct)
#pragma unroll
      for (int j = 0; j < 4; ++j)
        ti_bf[hbase + (size_t)(w * 16 + lk * 4 + j) * HD + colbase + ct * 16 + lrow] =
            f2bf(acco[ct][j]);
  }
}

// ---------------------------------------------------------------- transform GEMM
// m201-style 256x256 / BK=64 / 8 waves (2Mx4N) / 8-phase per 2 K-tiles.
// LDS 128KB: 2 bufs x { A: 2x16KB halves, B: 2x16KB halves }, 3-bit XOR swizzle.
// R4 change: NO manual lgkmcnt(0) drain before MFMA clusters — compiler emits
// fine-grained counted lgkm waits, so ds_reads overlap MFMA. Barriers +
// phase-end sched_barrier(0) retained (staging race-freedom proof in R3/R4
// analysis: every region's reads are pinned before their first in-phase MFMA
// consumer, and overwrites are issued only after the following barrier).

__global__ __launch_bounds__(512) void gemm_kernel(
    const unsigned short* __restrict__ hid_bf,  // [M][1024]
    const unsigned short* __restrict__ ti_bf,   // [M][1024]
    const unsigned short* __restrict__ Wt_bf,   // [1024][2048]  (n-major)
    const float* __restrict__ bias,             // [1024]
    float* __restrict__ out)                    // [M][1024]
{
  __shared__ unsigned short lds[65536];  // 128 KiB

  const int tid = threadIdx.x;
  const int w = tid >> 6, l = tid & 63;
  const int wm = w >> 2, wn = w & 3;       // 2 x 4 wave grid
  const int lrow = l & 15, lk = l >> 4;

  // XCD-aware bijective swizzle (nwg = 512, divisible by 8)
  const int orig = blockIdx.y * 4 + blockIdx.x;
  const int lid = (orig & 7) * 64 + (orig >> 3);
  const int nbase = (lid & 3) * 256;
  const int mbase = (lid >> 2) * 256;

  // staging lane geometry: row-in-half = rd*64 + srow8; col chunk pre-swizzled
  const int srow8 = w * 8 + (l >> 3);           // 0..63
  const int scol = ((l & 7) ^ (l >> 3)) << 3;   // element col offset (swizzled)

  // ds_read swizzled chunk offsets (elements): chunk (kh*4+lk) ^ (row&7)
  const int ck0 = ((lk)     ^ (lrow & 7)) << 3;
  const int ck1 = ((4 + lk) ^ (lrow & 7)) << 3;

#define STAGE_A(s, bsel, h) do {                                               \
    const int k0_ = (s) * 64;                                                  \
    const unsigned short* p_ = (k0_ < 1024) ? (hid_bf + k0_)                   \
                                            : (ti_bf + (k0_ - 1024));          \
    _Pragma("unroll")                                                          \
    for (int rd_ = 0; rd_ < 2; ++rd_)                                          \
      gll16(p_ + (size_t)(mbase + (h) * 128 + rd_ * 64 + srow8) * HD + scol,   \
            lds + (bsel) * 32768 + (h) * 8192 + rd_ * 4096 + w * 512);         \
  } while (0)

#define STAGE_B(s, bsel, h) do {                                               \
    const int k0_ = (s) * 64;                                                  \
    _Pragma("unroll")                                                          \
    for (int rd_ = 0; rd_ < 2; ++rd_)                                          \
      gll16(Wt_bf + (size_t)(nbase + (h) * 128 + rd_ * 64 + srow8) * FF        \
                  + k0_ + scol,                                                \
            lds + (bsel) * 32768 + 16384 + (h) * 8192 + rd_ * 4096 + w * 512); \
  } while (0)

#define PH_MID do {                                                            \
    __builtin_amdgcn_s_barrier();                                              \
    __builtin_amdgcn_s_setprio(1);                                             \
  } while (0)

#define PH_END do {                                                            \
    __builtin_amdgcn_s_setprio(0);                                             \
    __builtin_amdgcn_sched_barrier(0);                                         \
    __builtin_amdgcn_s_barrier();                                              \
  } while (0)

  f32x4 acc[8][4] = {};
  bf16x8 aR[4][2], bR[4][2];

  // prologue: A0,A1,B0,B1(tile0); B0,B1(tile1). vmcnt(4) -> tile0 landed.
  STAGE_A(0, 0, 0); STAGE_A(0, 0, 1);
  STAGE_B(0, 0, 0); STAGE_B(0, 0, 1);
  STAGE_B(1, 1, 0); STAGE_B(1, 1, 1);
  asm volatile("s_waitcnt vmcnt(4)" ::: "memory");
  __builtin_amdgcn_sched_barrier(0);
  __builtin_amdgcn_s_barrier();

#define TILE(tt, c) do {                                                       \
    const int sa_ = ((tt) + 1 > 31) ? 31 : (tt) + 1;                           \
    const int sb_ = ((tt) + 2 > 31) ? 31 : (tt) + 2;                           \
    const int abase_ = (c) * 32768 + wm * 8192 + lrow * 64;                    \
    const int bbase_ = (c) * 32768 + 16384 + (wn >> 1) * 8192                  \
                       + ((wn & 1) * 64 + lrow) * 64;                          \
    /* ---- P0: a[0..3], b[0..1]; stage A0(tt+1); MFMA m0-3 x n0-1 ---- */     \
    _Pragma("unroll")                                                          \
    for (int m_ = 0; m_ < 4; ++m_) {                                           \
      aR[m_][0] = *(const bf16x8*)(lds + abase_ + m_ * 1024 + ck0);            \
      aR[m_][1] = *(const bf16x8*)(lds + abase_ + m_ * 1024 + ck1);            \
    }                                                                          \
    _Pragma("unroll")                                                          \
    for (int n_ = 0; n_ < 2; ++n_) {                                           \
      bR[n_][0] = *(const bf16x8*)(lds + bbase_ + n_ * 1024 + ck0);            \
      bR[n_][1] = *(const bf16x8*)(lds + bbase_ + n_ * 1024 + ck1);            \
    }                                                                          \
    STAGE_A(sa_, 1 - (c), 0);                                                  \
    PH_MID;                                                                    \
    _Pragma("unroll")                                                          \
    for (int m_ = 0; m_ < 4; ++m_)                                             \
      _Pragma("unroll")                                                        \
      for (int n_ = 0; n_ < 2; ++n_) {                                         \
        acc[m_][n_] = __builtin_amdgcn_mfma_f32_16x16x32_bf16(                 \
            aR[m_][0], bR[n_][0], acc[m_][n_], 0, 0, 0);                       \
        acc[m_][n_] = __builtin_amdgcn_mfma_f32_16x16x32_bf16(                 \
            aR[m_][1], bR[n_][1], acc[m_][n_], 0, 0, 0);                       \
      }                                                                        \
    PH_END;                                                                    \
    /* ---- P1: b[2..3]; stage A1(tt+1); MFMA m0-3 x n2-3 ---- */              \
    _Pragma("unroll")                                                          \
    for (int n_ = 2; n_ < 4; ++n_) {                                           \
      bR[n_][0] = *(const bf16x8*)(lds + bbase_ + n_ * 1024 + ck0);            \
      bR[n_][1] = *(const bf16x8*)(lds + bbase_ + n_ * 1024 + ck1);            \
    }                                                                          \
    STAGE_A(sa_, 1 - (c), 1);                                                  \
    PH_MID;                                                                    \
    _Pragma("unroll")                                                          \
    for (int m_ = 0; m_ < 4; ++m_)                                             \
      _Pragma("unroll")                                                        \
      for (int n_ = 2; n_ < 4; ++n_) {                                         \
        acc[m_][n_] = __builtin_amdgcn_mfma_f32_16x16x32_bf16(                 \
            aR[m_][0], bR[n_][0], acc[m_][n_], 0, 0, 0);                       \
        acc[m_][n_] = __builtin_amdgcn_mfma_f32_16x16x32_bf16(                 \
            aR[m_][1], bR[n_][1], acc[m_][n_], 0, 0, 0);                       \
      }                                                                        \
    PH_END;                                                                    \
    /* ---- P2: a[4..7] (reuse regs); stage B0(tt+2); MFMA m4-7 x n0-1 ---- */ \
    _Pragma("unroll")                                                          \
    for (int m_ = 0; m_ < 4; ++m_) {                                           \
      aR[m_][0] = *(const bf16x8*)(lds + abase_ + (m_ + 4) * 1024 + ck0);      \
      aR[m_][1] = *(const bf16x8*)(lds + abase_ + (m_ + 4) * 1024 + ck1);      \
    }                                                                          \
    STAGE_B(sb_, (c), 0);                                                      \
    PH_MID;                                                                    \
    _Pragma("unroll")                                                          \
    for (int m_ = 0; m_ < 4; ++m_)                                             \
      _Pragma("unroll")                                                        \
      for (int n_ = 0; n_ < 2; ++n_) {                                         \
        acc[m_ + 4][n_] = __builtin_amdgcn_mfma_f32_16x16x32_bf16(             \
            aR[m_][0], bR[n_][0], acc[m_ + 4][n_], 0, 0, 0);                   \
        acc[m_ + 4][n_] = __builtin_amdgcn_mfma_f32_16x16x32_bf16(             \
            aR[m_][1], bR[n_][1], acc[m_ + 4][n_], 0, 0, 0);                   \
      }                                                                        \
    PH_END;                                                                    \
    /* ---- P3: no reads; stage B1(tt+2); MFMA m4-7 x n2-3; vmcnt(4) ---- */   \
    STAGE_B(sb_, (c), 1);                                                      \
    PH_MID;                                                                    \
    _Pragma("unroll")                                                          \
    for (int m_ = 0; m_ < 4; ++m_)                                             \
      _Pragma("unroll")                                                        \
      for (int n_ = 2; n_ < 4; ++n_) {                                         \
        acc[m_ + 4][n_] = __builtin_amdgcn_mfma_f32_16x16x32_bf16(             \
            aR[m_][0], bR[n_][0], acc[m_ + 4][n_], 0, 0, 0);                   \
        acc[m_ + 4][n_] = __builtin_amdgcn_mfma_f32_16x16x32_bf16(             \
            aR[m_][1], bR[n_][1], acc[m_ + 4][n_], 0, 0, 0);                   \
      }                                                                        \
    __builtin_amdgcn_s_setprio(0);                                             \
    asm volatile("s_waitcnt vmcnt(4)" ::: "memory");                           \
    __builtin_amdgcn_sched_barrier(0);                                         \
    __builtin_amdgcn_s_barrier();                                              \
  } while (0)

  for (int tt = 0; tt < 32; tt += 2) {
    TILE(tt, 0);
    TILE(tt + 1, 1);
  }
#undef TILE
#undef PH_MID
#undef PH_END
#undef STAGE_A
#undef STAGE_B

  // epilogue: tanh + bias + bf16 residual (hid_bf is L2/L3-warm from staging)
#pragma unroll
  for (int m = 0; m < 8; ++m) {
    const int row = mbase + wm * 128 + m * 16 + lk * 4;
#pragma unroll
    for (int n = 0; n < 4; ++n) {
      const int col = nbase + wn * 64 + n * 16 + lrow;
      const float bv = bias[col];
#pragma unroll
      for (int j = 0; j < 4; ++j) {
        float x = acc[m][n][j] + bv;
        float xc = fminf(fmaxf(x, -15.f), 15.f);
        float e2 = __expf(2.f * xc);
        float th = (e2 - 1.f) / (e2 + 1.f);
        size_t oi = (size_t)(row + j) * HD + col;
        unsigned int u = ((unsigned int)hid_bf[oi]) << 16;
        out[oi] = th + __builtin_bit_cast(float, u);
      }
    }
  }
}

// ---------------------------------------------------------------- launch
extern "C" void kernel_launch(void* const* d_in, const int* in_sizes, int n_in,
                              void* d_out, int out_size, void* d_ws, size_t ws_size,
                              hipStream_t stream) {
  const float* tgt  = (const float*)d_in[0];  // (B,T,2H)
  const float* hid  = (const float*)d_in[1];  // (B,S,2H)
  const float* W    = (const float*)d_in[2];  // (4H,2H)
  const float* bias = (const float*)d_in[3];  // (2H,)
  float* out = (float*)d_out;

  char* ws = (char*)d_ws;
  unsigned short* hid_bf  = (unsigned short*)(ws);                    //  64 MiB
  unsigned short* ti_bf   = (unsigned short*)(ws + 67108864);         //  64 MiB
  unsigned short* tgt_bf  = (unsigned short*)(ws + 134217728);        //   4 MiB
  unsigned short* tgtT_bf = (unsigned short*)(ws + 138412032);        //   4 MiB
  unsigned short* Wt_bf   = (unsigned short*)(ws + 142606336);        //   4 MiB

  cvt_bf16_kernel<<<2048, 256, 0, stream>>>(hid, hid_bf, (BB * SS * HD) / 4);
  cvt_bf16_kernel<<<512, 256, 0, stream>>>(tgt, tgt_bf, (BB * TT * HD) / 4);
  tcvt_kernel<<<dim3(HD / 32, TT / 32, BB), dim3(32, 8), 0, stream>>>(tgt, tgtT_bf, TT, HD);
  tcvt_kernel<<<dim3(HD / 32, FF / 32, 1), dim3(32, 8), 0, stream>>>(W, Wt_bf, FF, HD);
  attn_kernel<<<dim3(SS / 64, BB), 256, 0, stream>>>(hid_bf, tgt_bf, tgtT_bf, ti_bf);
  gemm_kernel<<<dim3(HD / 128 / 2, MM / 256), 512, 0, stream>>>(hid_bf, ti_bf, Wt_bf, bias, out);
}